// Round 19
// baseline (2133.729 us; speedup 1.0000x reference)
//
#include <hip/hip_runtime.h>
#include <hip/hip_bf16.h>
#include <cfloat>
#include <cstddef>

#define BB 16
#define NN 2048
#define KNN 30
#define MC 8192   // final-MLP chunk rows

using bf16 = __hip_bfloat16;
typedef short short8 __attribute__((ext_vector_type(8)));
typedef float floatx4 __attribute__((ext_vector_type(4)));

// ---- static device scratch (< 54.4 MB proven-good; loader aborts somewhere below 67.5 MB) ----
constexpr size_t XT_O  = 0;
constexpr size_t NRM_O = XT_O  + (size_t)BB*64*NN;
constexpr size_t A_O   = NRM_O + (size_t)BB*NN;
constexpr size_t U_O   = A_O   + (size_t)BB*NN*64;
constexpr size_t H_O   = U_O   + (size_t)BB*NN*64;      // 6,324,224 floats
constexpr size_t WS_F  = H_O   + (size_t)BB*NN*192;     // 12,615,680 floats = 50.5 MB
// final-MLP aliases over dead XT/nrm/A/U span (short offsets into (short*)g_ws):
constexpr size_t H1C_S = 0;                              // 8192*1024 shorts -> ends fl 4,194,304
constexpr size_t H2C_S = 8388608;                        // 8192*256  shorts -> ends fl 5,242,880
constexpr size_t H3C_S = 10485760;                       // 8192*128  shorts (bf16 H3) -> ends fl 5,767,168
constexpr size_t WB_S  = 11534336;                       // weights base (fl 5,767,168)
constexpr size_t WB1_S = WB_S + 0;                       // 196,608 shorts
constexpr size_t WB2_S = WB_S + 196608;                  // 262,144 shorts
constexpr size_t WB3_S = WB_S + 458752;                  // 32,768 shorts -> ends fl 6,012,928 < H_O ✓

__device__ __attribute__((aligned(16))) float g_ws[WS_F];
__device__ int   g_idx[(size_t)BB*NN*KNN];
__device__ int   g_isbf16;                               // runtime input-dtype flag (measured: fp32 world)

__device__ __forceinline__ float b2f(bf16 x){ return __bfloat162float(x); }
__device__ __forceinline__ float ldi(const void* p, size_t i){
  return g_isbf16 ? b2f(((const bf16*)p)[i]) : ((const float*)p)[i];
}
__device__ __forceinline__ short f2bs(float v){
  bf16 h = __float2bfloat16(v);
  return *reinterpret_cast<short*>(&h);
}
__device__ __forceinline__ float bs2f(short s){
  bf16 h = *reinterpret_cast<bf16*>(&s);
  return __bfloat162float(h);
}

// ---------------------------------------------------------------- dtype sniffer
__global__ __launch_bounds__(256) void k_sniff(const unsigned* __restrict__ posw){
  __shared__ int cnt[256];
  const int tid = threadIdx.x;
  int c = 0;
  for(int k=0;k<8;k++){
    unsigned w = posw[tid*8+k];
    unsigned code = (w & 0x7F80u) >> 7;
    if(code >= 119u && code <= 129u) c++;
  }
  cnt[tid] = c; __syncthreads();
  for(int s=128;s>0;s>>=1){ if(tid<s) cnt[tid]+=cnt[tid+s]; __syncthreads(); }
  if(tid==0) g_isbf16 = (cnt[0] > 1024) ? 1 : 0;
}

// ---------------------------------------------------------------- diagnostic
__global__ __launch_bounds__(256) void k_diag(bf16* __restrict__ out, int n, float v){
  int t = blockIdx.x*256 + threadIdx.x;
  if(t < n) out[t] = __float2bfloat16(v);
}

// ---------------------------------------------------------------- prep
__global__ __launch_bounds__(256) void k_prep(const void* __restrict__ pos){
  int t = blockIdx.x*256 + threadIdx.x;            // grid=128 -> t < 32768 exactly
  int b = t >> 11, i = t & (NN-1);
  float x = ldi(pos, (size_t)t*3+0), y = ldi(pos, (size_t)t*3+1), z = ldi(pos, (size_t)t*3+2);
  float* Xb = g_ws + XT_O + (size_t)b*64*NN;
  Xb[0*NN+i] = x; Xb[1*NN+i] = y; Xb[2*NN+i] = z;
  g_ws[NRM_O + t] = x*x + y*y + z*z;
}

// ---------------------------------------------------------------- kNN: barrier-free wave-local top-30
// R18 post-mortem: selection ~9K of 19K busy cyc/wave; the owner-rescan body mask-executed EVERY
// extraction (one lane always active -> no execz skip). Fix: top-2 lazy rescan — lane keeps the two
// lex-smallest (v,j); on win promote v2 (4 inst); full rescan only on 2nd-consecutive win
// (expected ~7/30, and the branch genuinely skips otherwise). Tie semantics identical: lex (v,j).
template<int C>
__global__ __launch_bounds__(256) void k_knn(){
  const int tid  = threadIdx.x;
  const int wid  = tid >> 6, lane = tid & 63;
  const int b    = blockIdx.x >> 9;                // 512 blocks per batch
  const int i0   = (blockIdx.x & 511) * 4;         // 4 query rows
  __shared__ float dlds[4][NN];                    // 32 KB
  __shared__ float xi[4][C];
  __shared__ float nI[4];
  const float* Xb  = g_ws + XT_O + (size_t)b*64*NN;
  const float* nrm = g_ws + NRM_O;
  for(int t = tid; t < 4*C; t += 256){
    int r = t / C, c = t - r*C;
    xi[r][c] = Xb[c*NN + i0 + r];
  }
  if(tid < 4) nI[tid] = nrm[b*NN + i0 + tid];
  __syncthreads();

  float nj[8];
  float dot[4][8];
  #pragma unroll
  for(int s=0;s<8;s++) nj[s] = nrm[b*NN + tid + s*256];
  #pragma unroll
  for(int r=0;r<4;r++){
    #pragma unroll
    for(int s=0;s<8;s++) dot[r][s] = 0.f;
  }
  for(int c=0;c<C;c++){
    float vj[8];
    #pragma unroll
    for(int s=0;s<8;s++) vj[s] = Xb[c*NN + tid + s*256];   // coalesced; reused by 4 rows
    #pragma unroll
    for(int r=0;r<4;r++){
      float xc = xi[r][c];
      #pragma unroll
      for(int s=0;s<8;s++) dot[r][s] = fmaf(xc, vj[s], dot[r][s]);
    }
  }
  #pragma unroll
  for(int r=0;r<4;r++){
    float nIr = nI[r];
    #pragma unroll
    for(int s=0;s<8;s++) dlds[r][tid + s*256] = fmaf(-2.f, dot[r][s], nIr + nj[s]);
  }
  __syncthreads();

  // wave 'wid' owns row 'wid': lane's candidate set {lane + 64q, q in [0,32)}
  float* drow = dlds[wid];
  float v1 = FLT_MAX, v2 = FLT_MAX; int j1 = 1<<30, j2 = 1<<30;
  #pragma unroll
  for(int q=0;q<32;q++){
    float x = drow[lane + (q<<6)]; int j = lane + (q<<6);
    if(x < v1 || (x == v1 && j < j1)){ v2 = v1; j2 = j1; v1 = x; j1 = j; }
    else if(x < v2 || (x == v2 && j < j2)){ v2 = x; j2 = j; }
  }
  bool known = true;
  const size_t rowbase = ((size_t)b*NN + i0 + wid)*KNN;
  for(int kk=0; kk<KNN; kk++){
    float bv = v1; int bj = j1;
    #pragma unroll
    for(int off=32; off>0; off>>=1){
      float ov = __shfl_xor(bv, off, 64);
      int   oj = __shfl_xor(bj, off, 64);
      if(ov < bv || (ov == bv && oj < bj)){ bv = ov; bj = oj; }
    }
    if(lane == 0) g_idx[rowbase + kk] = bj;          // bj uniform post-butterfly
    if(j1 == bj){                                    // unique owner (disjoint j-sets)
      drow[bj] = FLT_MAX;                            // consume slot
      if(known){ v1 = v2; j1 = j2; known = false; }  // cheap promote
      else {                                         // 2nd consecutive win: rescan top-2
        v1 = FLT_MAX; v2 = FLT_MAX; j1 = 1<<30; j2 = 1<<30;
        #pragma unroll
        for(int q=0;q<32;q++){
          float x = drow[lane + (q<<6)]; int j = lane + (q<<6);
          if(x < v1 || (x == v1 && j < j1)){ v2 = v1; j2 = j1; v1 = x; j1 = j; }
          else if(x < v2 || (x == v2 && j < j2)){ v2 = x; j2 = j; }
        }
        known = true;
      }
    }
  }
}

// ---------------------------------------------------------------- per-point precompute: A = x·(W0a-W0b)+b0, U = x·W0b
template<int C, bool EXTIN>
__global__ __launch_bounds__(256) void k_stage_pre(const void* __restrict__ Xin, int xOff,
    int rowStride, int colOff, const void* __restrict__ W0, const void* __restrict__ b0){
  __shared__ float Wd[C*64];
  __shared__ float Wb[C*64];
  __shared__ float bb[64];
  __shared__ float xs[4][C];
  const int tid = threadIdx.x;
  for(int t=tid; t<C*64; t+=256){
    float top = ldi(W0, t), bot = ldi(W0, (size_t)C*64 + t);
    Wd[t] = top - bot; Wb[t] = bot;
  }
  if(tid < 64) bb[tid] = ldi(b0, tid);
  const int wid = tid >> 6, lane = tid & 63;
  const int point = blockIdx.x*4 + wid;
  if(lane < C){
    float x;
    if(EXTIN) x = ldi(Xin, (size_t)point*rowStride + colOff + lane);
    else      x = g_ws[(size_t)xOff + (size_t)point*rowStride + colOff + lane];
    xs[wid][lane] = x;
  }
  __syncthreads();
  float a = bb[lane], u = 0.f;
  for(int c=0;c<C;c++){
    float xc = xs[wid][c];
    a = fmaf(xc, Wd[c*64 + lane], a);
    u = fmaf(xc, Wb[c*64 + lane], u);
  }
  g_ws[A_O + (size_t)point*64 + lane] = a;
  g_ws[U_O + (size_t)point*64 + lane] = u;
}

// ---------------------------------------------------------------- edge agg: max_k( relu(a_i+u_j) @ W1 + b1 )
// MFMA dot (R18, verified): h1 staged as bf16 hi/lo planes, W1 pre-split hi/lo in registers;
// D = ah*wh + ah*wl + al*wh (fp32 acc). Epilogue: masked max over m, quad shuffles, +bias after max.
template<bool WRITE_NEXT>
__global__ __launch_bounds__(256) void k_edge_agg(const void* __restrict__ W1,
    const void* __restrict__ b1, int colOff){
  __shared__ short hk_hi[4][32][64] __attribute__((aligned(16)));  // 16 KB
  __shared__ short hk_lo[4][32][64] __attribute__((aligned(16)));  // 16 KB
  const int tid = threadIdx.x;
  const int wid = tid >> 6, lane = tid & 63;
  const int ml = lane & 15, kgl = lane >> 4;
  short8 wh[2][4], wl[2][4];
  #pragma unroll
  for(int kt=0; kt<2; kt++)
    #pragma unroll
    for(int nt=0; nt<4; nt++)
      #pragma unroll
      for(int j=0; j<8; j++){
        float w = ldi(W1, (size_t)(kt*32 + kgl*8 + j)*64 + nt*16 + ml);
        short hi = f2bs(w);
        wh[kt][nt][j] = hi;
        wl[kt][nt][j] = f2bs(w - bs2f(hi));
      }
  const float bias = ldi(b1, lane);
  hk_hi[wid][30][lane] = 0; hk_hi[wid][31][lane] = 0;
  hk_lo[wid][30][lane] = 0; hk_lo[wid][31][lane] = 0;
  for(int pp=0; pp<4; pp++){
    const int point = blockIdx.x*16 + wid*4 + pp;
    const int b = point >> 11, i = point & (NN-1);
    const float a = g_ws[A_O + (size_t)point*64 + lane];
    const int* ip = g_idx + (size_t)point*KNN;
    const float* Ub = g_ws + U_O + (size_t)b*NN*64;
    int jv = 0;
    if(lane < KNN) jv = ip[lane] & (NN-1);             // one coalesced load; clamp = fault guard
    #pragma unroll
    for(int kk=0; kk<KNN; kk++){
      int j = __shfl(jv, kk, 64);
      float h = fmaxf(a + Ub[(size_t)j*64 + lane], 0.f);
      short hi = f2bs(h);
      hk_hi[wid][kk][lane] = hi;
      hk_lo[wid][kk][lane] = f2bs(h - bs2f(hi));
    }
    floatx4 acc[2][4];
    #pragma unroll
    for(int t=0;t<2;t++)
      #pragma unroll
      for(int nt=0;nt<4;nt++) acc[t][nt] = (floatx4){0.f,0.f,0.f,0.f};
    #pragma unroll
    for(int t=0;t<2;t++){
      #pragma unroll
      for(int kt=0;kt<2;kt++){
        short8 ah = *(const short8*)&hk_hi[wid][t*16+ml][kt*32 + kgl*8];
        short8 al = *(const short8*)&hk_lo[wid][t*16+ml][kt*32 + kgl*8];
        #pragma unroll
        for(int nt=0;nt<4;nt++){
          acc[t][nt] = __builtin_amdgcn_mfma_f32_16x16x32_bf16(ah, wh[kt][nt], acc[t][nt], 0,0,0);
          acc[t][nt] = __builtin_amdgcn_mfma_f32_16x16x32_bf16(ah, wl[kt][nt], acc[t][nt], 0,0,0);
          acc[t][nt] = __builtin_amdgcn_mfma_f32_16x16x32_bf16(al, wh[kt][nt], acc[t][nt], 0,0,0);
        }
      }
    }
    float cmax[4];
    #pragma unroll
    for(int nt=0;nt<4;nt++){
      float mx = -FLT_MAX;
      #pragma unroll
      for(int t=0;t<2;t++)
        #pragma unroll
        for(int reg=0;reg<4;reg++){
          int m = t*16 + kgl*4 + reg;
          if(m < KNN) mx = fmaxf(mx, acc[t][nt][reg]);
        }
      mx = fmaxf(mx, __shfl_xor(mx, 16, 64));
      mx = fmaxf(mx, __shfl_xor(mx, 32, 64));
      cmax[nt] = mx;
    }
    float r01 = (lane & 16) ? cmax[1] : cmax[0];
    float r23 = (lane & 16) ? cmax[3] : cmax[2];
    float accf = ((lane & 32) ? r23 : r01) + bias;
    g_ws[H_O + (size_t)point*192 + colOff + lane] = accf;
    if(WRITE_NEXT){
      g_ws[XT_O + ((size_t)b*64 + lane)*NN + i] = accf; // transposed copy for next kNN
      float sq = accf*accf;
      #pragma unroll
      for(int off=32; off>0; off>>=1) sq += __shfl_xor(sq, off, 64);
      if(lane == 0) g_ws[NRM_O + point] = sq;
    }
  }
}

// ---------------------------------------------------------------- weight preconvert: fp32 [K][N] -> fragment-major bf16
__global__ __launch_bounds__(256) void k_wconv(const void* __restrict__ W, int dstOffS,
                                               int total, int log2N){
  int t = blockIdx.x*256 + threadIdx.x;
  if(t >= total) return;
  int k = t >> log2N, n = t & ((1<<log2N)-1);
  short* dst = (short*)g_ws + dstOffS;
  dst[((size_t)((k>>3) << log2N) + ((size_t)n))*8 + (k&7)] = f2bs(ldi(W, t));
}

// ---------------------------------------------------------------- MFMA GEMM: Out = act(A @ W + bias)
// Block 256 = 2x2 waves, tile 128x128, wave 64x64, K-step 32, mfma_f32_16x16x32_bf16.
template<bool ABF16, bool RELU, bool OUTBF16>
__global__ __launch_bounds__(256) void k_mgemm(int aOff, int wOffS, const void* __restrict__ bias,
    int outOff, int Kd, int Nn){
  __shared__ short As[4*128*8] __attribute__((aligned(16)));   // [kg][m][j] 8 KB
  __shared__ short Bs[4*128*8] __attribute__((aligned(16)));   // [kg][n][j] 8 KB
  const int tid = threadIdx.x;
  const int lane = tid & 63, wid = tid >> 6;
  const int waveM = wid >> 1, waveN = wid & 1;
  const int m0 = blockIdx.x * 128, n0 = blockIdx.y * 128;
  const int sm = tid >> 1, skg0 = (tid & 1) * 2;     // A-stage: row sm, k-groups skg0,skg0+1
  const int bn = tid & 127, bkg = tid >> 7;          // B-stage: n, k-groups bkg, bkg+2
  const short* Wb = (const short*)g_ws + wOffS;
  floatx4 acc[4][4];
  #pragma unroll
  for(int a=0;a<4;a++)
    #pragma unroll
    for(int bq=0;bq<4;bq++) acc[a][bq] = (floatx4){0.f,0.f,0.f,0.f};

  for(int k0 = 0; k0 < Kd; k0 += 32){
    if(ABF16){
      const short* Ab = (const short*)g_ws + aOff + (size_t)(m0+sm)*Kd + k0 + skg0*8;
      short8 v0 = *(const short8*)Ab;
      short8 v1 = *(const short8*)(Ab+8);
      *(short8*)&As[((skg0  )*128 + sm)*8] = v0;
      *(short8*)&As[((skg0+1)*128 + sm)*8] = v1;
    } else {
      const float* Af = g_ws + aOff + (size_t)(m0+sm)*Kd + k0 + skg0*8;
      float4 f0 = *(const float4*)(Af+0);
      float4 f1 = *(const float4*)(Af+4);
      float4 f2 = *(const float4*)(Af+8);
      float4 f3 = *(const float4*)(Af+12);
      short8 s0, s1;
      s0[0]=f2bs(f0.x); s0[1]=f2bs(f0.y); s0[2]=f2bs(f0.z); s0[3]=f2bs(f0.w);
      s0[4]=f2bs(f1.x); s0[5]=f2bs(f1.y); s0[6]=f2bs(f1.z); s0[7]=f2bs(f1.w);
      s1[0]=f2bs(f2.x); s1[1]=f2bs(f2.y); s1[2]=f2bs(f2.z); s1[3]=f2bs(f2.w);
      s1[4]=f2bs(f3.x); s1[5]=f2bs(f3.y); s1[6]=f2bs(f3.z); s1[7]=f2bs(f3.w);
      *(short8*)&As[((skg0  )*128 + sm)*8] = s0;
      *(short8*)&As[((skg0+1)*128 + sm)*8] = s1;
    }
    #pragma unroll
    for(int i=0;i<2;i++){
      int kg = bkg + i*2;
      const short* src = Wb + ((size_t)((k0>>3) + kg)*Nn + n0 + bn)*8;
      *(short8*)&Bs[(kg*128 + bn)*8] = *(const short8*)src;
    }
    __syncthreads();
    const int kgl = lane >> 4, ml = lane & 15;
    short8 af[4], bf[4];
    #pragma unroll
    for(int t=0;t<4;t++){
      af[t] = *(const short8*)&As[(kgl*128 + waveM*64 + t*16 + ml)*8];
      bf[t] = *(const short8*)&Bs[(kgl*128 + waveN*64 + t*16 + ml)*8];
    }
    #pragma unroll
    for(int tm=0;tm<4;tm++)
      #pragma unroll
      for(int tn=0;tn<4;tn++)
        acc[tm][tn] = __builtin_amdgcn_mfma_f32_16x16x32_bf16(af[tm], bf[tn], acc[tm][tn], 0, 0, 0);
    __syncthreads();
  }
  // epilogue: D col=lane&15, row=(lane>>4)*4+reg  [m89]
  const int kgl = lane >> 4, ml = lane & 15;
  #pragma unroll
  for(int tn=0;tn<4;tn++){
    int n = n0 + waveN*64 + tn*16 + ml;
    float bv = ldi(bias, n);
    #pragma unroll
    for(int tm=0;tm<4;tm++){
      #pragma unroll
      for(int reg=0;reg<4;reg++){
        int m = m0 + waveM*64 + tm*16 + kgl*4 + reg;
        float v = acc[tm][tn][reg] + bv;
        if(RELU) v = fmaxf(v, 0.f);
        if(OUTBF16) ((short*)g_ws)[(size_t)outOff + (size_t)m*Nn + n] = f2bs(v);
        else        g_ws[(size_t)outOff + (size_t)m*Nn + n] = v;
      }
    }
  }
}

// ---------------------------------------------------------------- final 128->3 (H3 bf16), dtype-matched store
__global__ __launch_bounds__(256) void k_final(const void* __restrict__ FW,
    const void* __restrict__ FB, void* __restrict__ out, int outOff){
  __shared__ float wf[128*3];
  __shared__ float bf3[3];
  const int tid = threadIdx.x;
  for(int t=tid; t<384; t+=256) wf[t] = ldi(FW, t);
  if(tid < 3) bf3[tid] = ldi(FB, tid);
  __syncthreads();
  const int p = blockIdx.x*256 + tid;                // grid=32 -> p < 8192 exactly
  const short* h = (const short*)g_ws + H3C_S + (size_t)p*128;
  float a0 = bf3[0], a1 = bf3[1], a2 = bf3[2];
  #pragma unroll 8
  for(int c=0;c<128;c++){
    float x = bs2f(h[c]);
    a0 = fmaf(x, wf[c*3+0], a0);
    a1 = fmaf(x, wf[c*3+1], a1);
    a2 = fmaf(x, wf[c*3+2], a2);
  }
  size_t o = (size_t)outOff + (size_t)p*3;
  if(g_isbf16){
    bf16* ob = (bf16*)out;
    ob[o+0] = __float2bfloat16(a0); ob[o+1] = __float2bfloat16(a1); ob[o+2] = __float2bfloat16(a2);
  } else {
    float* of = (float*)out;
    of[o+0] = a0; of[o+1] = a1; of[o+2] = a2;
  }
}

extern "C" void kernel_launch(void* const* d_in, const int* in_sizes, int n_in,
                              void* d_out, int out_size, void* d_ws, size_t ws_size,
                              hipStream_t stream){
  (void)d_ws; (void)ws_size;
  static const int EXP[21] = {98304, 384,64, 4096,64, 8192,64, 4096,64, 8192,64, 4096,64,
                              196608,1024, 262144,256, 32768,128, 384,3};
  const void* in[21];
  int posmatch = 0;
  bool run = false;
  if(n_in == 21){
    for(int e=0; e<21; e++) posmatch += (in_sizes[e] == EXP[e]) ? 1 : 0;
    if(posmatch == 21){
      for(int e=0; e<21; e++) in[e] = d_in[e];
      run = true;
    } else {
      bool used[21] = {false}; const void* m[21]; bool ok = true;
      for(int e=0; e<21 && ok; e++){
        int hit = -1;
        for(int i2=0; i2<21; i2++)
          if(!used[i2] && in_sizes[i2] == EXP[e]){ hit = i2; break; }
        if(hit < 0) ok = false;
        else { used[hit] = true; m[e] = d_in[hit]; }
      }
      if(ok){ for(int e=0; e<21; e++) in[e] = m[e]; run = true; }
    }
  }
  if(!run){
    float V = 1000.f*(float)n_in + 10.f*(float)posmatch;
    k_diag<<<(out_size+255)/256, 256, 0, stream>>>((bf16*)d_out, out_size, V);
    return;
  }
  const void* pos  = in[0];
  const void* c1w0 = in[1];  const void* c1b0 = in[2];
  const void* c1w1 = in[3];  const void* c1b1 = in[4];
  const void* c2w0 = in[5];  const void* c2b0 = in[6];
  const void* c2w1 = in[7];  const void* c2b1 = in[8];
  const void* c3w0 = in[9];  const void* c3b0 = in[10];
  const void* c3w1 = in[11]; const void* c3b1 = in[12];
  const void* mw0  = in[13]; const void* mb0  = in[14];
  const void* mw1  = in[15]; const void* mb1  = in[16];
  const void* mw2  = in[17]; const void* mb2  = in[18];
  const void* fw   = in[19]; const void* fb   = in[20];

  dim3 b256(256);
  k_sniff<<<1, b256, 0, stream>>>((const unsigned*)pos);
  k_prep<<<128, b256, 0, stream>>>(pos);

  // stage 1 (C=3)
  k_knn<3><<<8192, b256, 0, stream>>>();
  k_stage_pre<3,true><<<8192, b256, 0, stream>>>(pos, 0, 3, 0, c1w0, c1b0);
  k_edge_agg<true><<<2048, b256, 0, stream>>>(c1w1, c1b1, 0);

  // stage 2 (C=64)
  k_knn<64><<<8192, b256, 0, stream>>>();
  k_stage_pre<64,false><<<8192, b256, 0, stream>>>(nullptr, (int)H_O, 192, 0, c2w0, c2b0);
  k_edge_agg<true><<<2048, b256, 0, stream>>>(c2w1, c2b1, 64);

  // stage 3 (C=64)
  k_knn<64><<<8192, b256, 0, stream>>>();
  k_stage_pre<64,false><<<8192, b256, 0, stream>>>(nullptr, (int)H_O, 192, 64, c3w0, c3b0);
  k_edge_agg<false><<<2048, b256, 0, stream>>>(c3w1, c3b1, 128);

  // weight preconvert AFTER stage 3 (targets alias U-region, dead from here on)
  k_wconv<<<768,  b256, 0, stream>>>(mw0, (int)WB1_S, 196608, 10);
  k_wconv<<<1024, b256, 0, stream>>>(mw1, (int)WB2_S, 262144, 8);
  k_wconv<<<128,  b256, 0, stream>>>(mw2, (int)WB3_S, 32768, 7);

  // final MLP: MFMA bf16, chunked M=8192 (4 chunks; H3 bf16 keeps alias span < H_O)
  for(int ch=0; ch<4; ch++){
    int ainOff = (int)(H_O + (size_t)ch*MC*192);
    k_mgemm<false,true ,true ><<<dim3(64,8), b256, 0, stream>>>(ainOff,     (int)WB1_S, mb0, (int)H1C_S, 192, 1024);
    k_mgemm<true ,true ,true ><<<dim3(64,2), b256, 0, stream>>>((int)H1C_S, (int)WB2_S, mb1, (int)H2C_S, 1024, 256);
    k_mgemm<true ,false,true ><<<dim3(64,1), b256, 0, stream>>>((int)H2C_S, (int)WB3_S, mb2, (int)H3C_S, 256, 128);
    k_final<<<32, b256, 0, stream>>>(fw, fb, d_out, ch*MC*3);
  }
}

// Round 20
// 1599.213 us; speedup vs baseline: 1.3342x; 1.3342x over previous
//
#include <hip/hip_runtime.h>
#include <hip/hip_bf16.h>
#include <cfloat>
#include <cstddef>

#define BB 16
#define NN 2048
#define KNN 30
#define MC 8192   // final-MLP chunk rows

using bf16 = __hip_bfloat16;
typedef short short8 __attribute__((ext_vector_type(8)));
typedef float floatx4 __attribute__((ext_vector_type(4)));

// ---- static device scratch (< 54.4 MB proven-good; loader aborts somewhere below 67.5 MB) ----
constexpr size_t XT_O  = 0;
constexpr size_t NRM_O = XT_O  + (size_t)BB*64*NN;
constexpr size_t A_O   = NRM_O + (size_t)BB*NN;
constexpr size_t U_O   = A_O   + (size_t)BB*NN*64;
constexpr size_t H_O   = U_O   + (size_t)BB*NN*64;      // 6,324,224 floats
constexpr size_t WS_F  = H_O   + (size_t)BB*NN*192;     // 12,615,680 floats = 50.5 MB
// final-MLP aliases over dead XT/nrm/A/U span (short offsets into (short*)g_ws):
constexpr size_t H1C_S = 0;                              // 8192*1024 shorts -> ends fl 4,194,304
constexpr size_t H2C_S = 8388608;                        // 8192*256  shorts -> ends fl 5,242,880
constexpr size_t H3C_S = 10485760;                       // 8192*128  shorts (bf16 H3) -> ends fl 5,767,168
constexpr size_t WB_S  = 11534336;                       // weights base (fl 5,767,168)
constexpr size_t WB1_S = WB_S + 0;                       // 196,608 shorts
constexpr size_t WB2_S = WB_S + 196608;                  // 262,144 shorts
constexpr size_t WB3_S = WB_S + 458752;                  // 32,768 shorts -> ends fl 6,012,928 < H_O ✓

__device__ __attribute__((aligned(16))) float g_ws[WS_F];
__device__ int   g_idx[(size_t)BB*NN*KNN];
__device__ int   g_isbf16;                               // runtime input-dtype flag (measured: fp32 world)

__device__ __forceinline__ float b2f(bf16 x){ return __bfloat162float(x); }
__device__ __forceinline__ float ldi(const void* p, size_t i){
  return g_isbf16 ? b2f(((const bf16*)p)[i]) : ((const float*)p)[i];
}
__device__ __forceinline__ short f2bs(float v){
  bf16 h = __float2bfloat16(v);
  return *reinterpret_cast<short*>(&h);
}
__device__ __forceinline__ float bs2f(short s){
  bf16 h = *reinterpret_cast<bf16*>(&s);
  return __bfloat162float(h);
}
// monotonic u32 key: order-isomorphic to float compare (incl. negatives)
__device__ __forceinline__ unsigned fmono(float x){
  unsigned u = __float_as_uint(x);
  return ((int)u < 0) ? ~u : (u | 0x80000000u);
}
// u64 lex-min with DPP-shifted partner (pure VALU pipe — replaces ds_bpermute shuffles)
template<int CTRL>
__device__ __forceinline__ unsigned long long dppmin(unsigned long long k){
  int lo = (int)(unsigned)(k & 0xFFFFFFFFull);
  int hi = (int)(unsigned)(k >> 32);
  int nlo = __builtin_amdgcn_update_dpp(lo, lo, CTRL, 0xF, 0xF, false);
  int nhi = __builtin_amdgcn_update_dpp(hi, hi, CTRL, 0xF, 0xF, false);
  unsigned long long kn = ((unsigned long long)(unsigned)nhi << 32) | (unsigned)nlo;
  return kn < k ? kn : k;
}

// ---------------------------------------------------------------- dtype sniffer
__global__ __launch_bounds__(256) void k_sniff(const unsigned* __restrict__ posw){
  __shared__ int cnt[256];
  const int tid = threadIdx.x;
  int c = 0;
  for(int k=0;k<8;k++){
    unsigned w = posw[tid*8+k];
    unsigned code = (w & 0x7F80u) >> 7;
    if(code >= 119u && code <= 129u) c++;
  }
  cnt[tid] = c; __syncthreads();
  for(int s=128;s>0;s>>=1){ if(tid<s) cnt[tid]+=cnt[tid+s]; __syncthreads(); }
  if(tid==0) g_isbf16 = (cnt[0] > 1024) ? 1 : 0;
}

// ---------------------------------------------------------------- diagnostic
__global__ __launch_bounds__(256) void k_diag(bf16* __restrict__ out, int n, float v){
  int t = blockIdx.x*256 + threadIdx.x;
  if(t < n) out[t] = __float2bfloat16(v);
}

// ---------------------------------------------------------------- prep
__global__ __launch_bounds__(256) void k_prep(const void* __restrict__ pos){
  int t = blockIdx.x*256 + threadIdx.x;            // grid=128 -> t < 32768 exactly
  int b = t >> 11, i = t & (NN-1);
  float x = ldi(pos, (size_t)t*3+0), y = ldi(pos, (size_t)t*3+1), z = ldi(pos, (size_t)t*3+2);
  float* Xb = g_ws + XT_O + (size_t)b*64*NN;
  Xb[0*NN+i] = x; Xb[1*NN+i] = y; Xb[2*NN+i] = z;
  g_ws[NRM_O + t] = x*x + y*y + z*z;
}

// ---------------------------------------------------------------- kNN: barrier-free wave-local top-30
// R19 post-mortem: top-2 lazy rescan regressed (435->538us) — reverted to R18 incremental-min.
// R18 arithmetic: ~11K cyc/wave of the selection was the __shfl_xor butterfly (ds_bpermute on the
// LDS pipe, 6 serialized round-trips x 30 extractions). Fix: dlds stores MONOTONIC u32 keys
// (order-isomorphic incl. lowest-j tie), extraction packs (key,j) in u64 and reduces via DPP
// (row_shr 1/2/4/8 + bcast15/31, pure VALU); winner j via readlane(63); owner invalidates+rescans.
template<int C>
__global__ __launch_bounds__(256) void k_knn(){
  const int tid  = threadIdx.x;
  const int wid  = tid >> 6, lane = tid & 63;
  const int b    = blockIdx.x >> 9;                // 512 blocks per batch
  const int i0   = (blockIdx.x & 511) * 4;         // 4 query rows
  __shared__ unsigned dlds[4][NN];                 // 32 KB, monotonic keys
  __shared__ float xi[4][C];
  __shared__ float nI[4];
  const float* Xb  = g_ws + XT_O + (size_t)b*64*NN;
  const float* nrm = g_ws + NRM_O;
  for(int t = tid; t < 4*C; t += 256){
    int r = t / C, c = t - r*C;
    xi[r][c] = Xb[c*NN + i0 + r];
  }
  if(tid < 4) nI[tid] = nrm[b*NN + i0 + tid];
  __syncthreads();

  float nj[8];
  float dot[4][8];
  #pragma unroll
  for(int s=0;s<8;s++) nj[s] = nrm[b*NN + tid + s*256];
  #pragma unroll
  for(int r=0;r<4;r++){
    #pragma unroll
    for(int s=0;s<8;s++) dot[r][s] = 0.f;
  }
  for(int c=0;c<C;c++){
    float vj[8];
    #pragma unroll
    for(int s=0;s<8;s++) vj[s] = Xb[c*NN + tid + s*256];   // coalesced; reused by 4 rows
    #pragma unroll
    for(int r=0;r<4;r++){
      float xc = xi[r][c];
      #pragma unroll
      for(int s=0;s<8;s++) dot[r][s] = fmaf(xc, vj[s], dot[r][s]);
    }
  }
  #pragma unroll
  for(int r=0;r<4;r++){
    float nIr = nI[r];
    #pragma unroll
    for(int s=0;s<8;s++) dlds[r][tid + s*256] = fmono(fmaf(-2.f, dot[r][s], nIr + nj[s]));
  }
  __syncthreads();

  // wave 'wid' owns row 'wid': lane's candidate set {lane + 64q, q in [0,32)}
  unsigned* drow = dlds[wid];
  unsigned mj = 0xFFFFFFFFu; int lj = lane;
  #pragma unroll
  for(int q=0;q<32;q++){
    unsigned m = drow[lane + (q<<6)];
    if(m < mj){ mj = m; lj = lane + (q<<6); }      // ascending q => lowest j kept on tie
  }
  const size_t rowbase = ((size_t)b*NN + i0 + wid)*KNN;
  for(int kk=0; kk<KNN; kk++){
    unsigned long long K = ((unsigned long long)mj << 32) | (unsigned)lj;
    K = dppmin<0x111>(K);                          // row_shr:1
    K = dppmin<0x112>(K);                          // row_shr:2
    K = dppmin<0x114>(K);                          // row_shr:4
    K = dppmin<0x118>(K);                          // row_shr:8
    K = dppmin<0x142>(K);                          // row_bcast:15
    K = dppmin<0x143>(K);                          // row_bcast:31 -> lane 63 = global argmin
    int bj = __builtin_amdgcn_readlane((int)(unsigned)(K & 0xFFFFFFFFull), 63);
    if(lane == 0) g_idx[rowbase + kk] = bj;
    if(lj == bj){                                  // unique owner (disjoint j-sets)
      drow[bj] = 0xFFFFFFFFu;                      // invalidate my winning slot
      mj = 0xFFFFFFFFu; lj = lane;
      #pragma unroll
      for(int q=0;q<32;q++){
        unsigned m = drow[lane + (q<<6)];
        if(m < mj){ mj = m; lj = lane + (q<<6); }
      }
    }
  }
}

// ---------------------------------------------------------------- per-point precompute: A = x·(W0a-W0b)+b0, U = x·W0b
template<int C, bool EXTIN>
__global__ __launch_bounds__(256) void k_stage_pre(const void* __restrict__ Xin, int xOff,
    int rowStride, int colOff, const void* __restrict__ W0, const void* __restrict__ b0){
  __shared__ float Wd[C*64];
  __shared__ float Wb[C*64];
  __shared__ float bb[64];
  __shared__ float xs[4][C];
  const int tid = threadIdx.x;
  for(int t=tid; t<C*64; t+=256){
    float top = ldi(W0, t), bot = ldi(W0, (size_t)C*64 + t);
    Wd[t] = top - bot; Wb[t] = bot;
  }
  if(tid < 64) bb[tid] = ldi(b0, tid);
  const int wid = tid >> 6, lane = tid & 63;
  const int point = blockIdx.x*4 + wid;
  if(lane < C){
    float x;
    if(EXTIN) x = ldi(Xin, (size_t)point*rowStride + colOff + lane);
    else      x = g_ws[(size_t)xOff + (size_t)point*rowStride + colOff + lane];
    xs[wid][lane] = x;
  }
  __syncthreads();
  float a = bb[lane], u = 0.f;
  for(int c=0;c<C;c++){
    float xc = xs[wid][c];
    a = fmaf(xc, Wd[c*64 + lane], a);
    u = fmaf(xc, Wb[c*64 + lane], u);
  }
  g_ws[A_O + (size_t)point*64 + lane] = a;
  g_ws[U_O + (size_t)point*64 + lane] = u;
}

// ---------------------------------------------------------------- edge agg: max_k( relu(a_i+u_j) @ W1 + b1 )
// MFMA dot (R18, verified): h1 staged as bf16 hi/lo planes, W1 pre-split hi/lo in registers;
// D = ah*wh + ah*wl + al*wh (fp32 acc). Epilogue: masked max over m, quad shuffles, +bias after max.
template<bool WRITE_NEXT>
__global__ __launch_bounds__(256) void k_edge_agg(const void* __restrict__ W1,
    const void* __restrict__ b1, int colOff){
  __shared__ short hk_hi[4][32][64] __attribute__((aligned(16)));  // 16 KB
  __shared__ short hk_lo[4][32][64] __attribute__((aligned(16)));  // 16 KB
  const int tid = threadIdx.x;
  const int wid = tid >> 6, lane = tid & 63;
  const int ml = lane & 15, kgl = lane >> 4;
  short8 wh[2][4], wl[2][4];
  #pragma unroll
  for(int kt=0; kt<2; kt++)
    #pragma unroll
    for(int nt=0; nt<4; nt++)
      #pragma unroll
      for(int j=0; j<8; j++){
        float w = ldi(W1, (size_t)(kt*32 + kgl*8 + j)*64 + nt*16 + ml);
        short hi = f2bs(w);
        wh[kt][nt][j] = hi;
        wl[kt][nt][j] = f2bs(w - bs2f(hi));
      }
  const float bias = ldi(b1, lane);
  hk_hi[wid][30][lane] = 0; hk_hi[wid][31][lane] = 0;
  hk_lo[wid][30][lane] = 0; hk_lo[wid][31][lane] = 0;
  for(int pp=0; pp<4; pp++){
    const int point = blockIdx.x*16 + wid*4 + pp;
    const int b = point >> 11, i = point & (NN-1);
    const float a = g_ws[A_O + (size_t)point*64 + lane];
    const int* ip = g_idx + (size_t)point*KNN;
    const float* Ub = g_ws + U_O + (size_t)b*NN*64;
    int jv = 0;
    if(lane < KNN) jv = ip[lane] & (NN-1);             // one coalesced load; clamp = fault guard
    #pragma unroll
    for(int kk=0; kk<KNN; kk++){
      int j = __shfl(jv, kk, 64);
      float h = fmaxf(a + Ub[(size_t)j*64 + lane], 0.f);
      short hi = f2bs(h);
      hk_hi[wid][kk][lane] = hi;
      hk_lo[wid][kk][lane] = f2bs(h - bs2f(hi));
    }
    floatx4 acc[2][4];
    #pragma unroll
    for(int t=0;t<2;t++)
      #pragma unroll
      for(int nt=0;nt<4;nt++) acc[t][nt] = (floatx4){0.f,0.f,0.f,0.f};
    #pragma unroll
    for(int t=0;t<2;t++){
      #pragma unroll
      for(int kt=0;kt<2;kt++){
        short8 ah = *(const short8*)&hk_hi[wid][t*16+ml][kt*32 + kgl*8];
        short8 al = *(const short8*)&hk_lo[wid][t*16+ml][kt*32 + kgl*8];
        #pragma unroll
        for(int nt=0;nt<4;nt++){
          acc[t][nt] = __builtin_amdgcn_mfma_f32_16x16x32_bf16(ah, wh[kt][nt], acc[t][nt], 0,0,0);
          acc[t][nt] = __builtin_amdgcn_mfma_f32_16x16x32_bf16(ah, wl[kt][nt], acc[t][nt], 0,0,0);
          acc[t][nt] = __builtin_amdgcn_mfma_f32_16x16x32_bf16(al, wh[kt][nt], acc[t][nt], 0,0,0);
        }
      }
    }
    float cmax[4];
    #pragma unroll
    for(int nt=0;nt<4;nt++){
      float mx = -FLT_MAX;
      #pragma unroll
      for(int t=0;t<2;t++)
        #pragma unroll
        for(int reg=0;reg<4;reg++){
          int m = t*16 + kgl*4 + reg;
          if(m < KNN) mx = fmaxf(mx, acc[t][nt][reg]);
        }
      mx = fmaxf(mx, __shfl_xor(mx, 16, 64));
      mx = fmaxf(mx, __shfl_xor(mx, 32, 64));
      cmax[nt] = mx;
    }
    float r01 = (lane & 16) ? cmax[1] : cmax[0];
    float r23 = (lane & 16) ? cmax[3] : cmax[2];
    float accf = ((lane & 32) ? r23 : r01) + bias;
    g_ws[H_O + (size_t)point*192 + colOff + lane] = accf;
    if(WRITE_NEXT){
      g_ws[XT_O + ((size_t)b*64 + lane)*NN + i] = accf; // transposed copy for next kNN
      float sq = accf*accf;
      #pragma unroll
      for(int off=32; off>0; off>>=1) sq += __shfl_xor(sq, off, 64);
      if(lane == 0) g_ws[NRM_O + point] = sq;
    }
  }
}

// ---------------------------------------------------------------- weight preconvert: fp32 [K][N] -> fragment-major bf16
__global__ __launch_bounds__(256) void k_wconv(const void* __restrict__ W, int dstOffS,
                                               int total, int log2N){
  int t = blockIdx.x*256 + threadIdx.x;
  if(t >= total) return;
  int k = t >> log2N, n = t & ((1<<log2N)-1);
  short* dst = (short*)g_ws + dstOffS;
  dst[((size_t)((k>>3) << log2N) + ((size_t)n))*8 + (k&7)] = f2bs(ldi(W, t));
}

// ---------------------------------------------------------------- MFMA GEMM: Out = act(A @ W + bias)
// Block 256 = 2x2 waves, tile 128x128, wave 64x64, K-step 32, mfma_f32_16x16x32_bf16.
template<bool ABF16, bool RELU, bool OUTBF16>
__global__ __launch_bounds__(256) void k_mgemm(int aOff, int wOffS, const void* __restrict__ bias,
    int outOff, int Kd, int Nn){
  __shared__ short As[4*128*8] __attribute__((aligned(16)));   // [kg][m][j] 8 KB
  __shared__ short Bs[4*128*8] __attribute__((aligned(16)));   // [kg][n][j] 8 KB
  const int tid = threadIdx.x;
  const int lane = tid & 63, wid = tid >> 6;
  const int waveM = wid >> 1, waveN = wid & 1;
  const int m0 = blockIdx.x * 128, n0 = blockIdx.y * 128;
  const int sm = tid >> 1, skg0 = (tid & 1) * 2;     // A-stage: row sm, k-groups skg0,skg0+1
  const int bn = tid & 127, bkg = tid >> 7;          // B-stage: n, k-groups bkg, bkg+2
  const short* Wb = (const short*)g_ws + wOffS;
  floatx4 acc[4][4];
  #pragma unroll
  for(int a=0;a<4;a++)
    #pragma unroll
    for(int bq=0;bq<4;bq++) acc[a][bq] = (floatx4){0.f,0.f,0.f,0.f};

  for(int k0 = 0; k0 < Kd; k0 += 32){
    if(ABF16){
      const short* Ab = (const short*)g_ws + aOff + (size_t)(m0+sm)*Kd + k0 + skg0*8;
      short8 v0 = *(const short8*)Ab;
      short8 v1 = *(const short8*)(Ab+8);
      *(short8*)&As[((skg0  )*128 + sm)*8] = v0;
      *(short8*)&As[((skg0+1)*128 + sm)*8] = v1;
    } else {
      const float* Af = g_ws + aOff + (size_t)(m0+sm)*Kd + k0 + skg0*8;
      float4 f0 = *(const float4*)(Af+0);
      float4 f1 = *(const float4*)(Af+4);
      float4 f2 = *(const float4*)(Af+8);
      float4 f3 = *(const float4*)(Af+12);
      short8 s0, s1;
      s0[0]=f2bs(f0.x); s0[1]=f2bs(f0.y); s0[2]=f2bs(f0.z); s0[3]=f2bs(f0.w);
      s0[4]=f2bs(f1.x); s0[5]=f2bs(f1.y); s0[6]=f2bs(f1.z); s0[7]=f2bs(f1.w);
      s1[0]=f2bs(f2.x); s1[1]=f2bs(f2.y); s1[2]=f2bs(f2.z); s1[3]=f2bs(f2.w);
      s1[4]=f2bs(f3.x); s1[5]=f2bs(f3.y); s1[6]=f2bs(f3.z); s1[7]=f2bs(f3.w);
      *(short8*)&As[((skg0  )*128 + sm)*8] = s0;
      *(short8*)&As[((skg0+1)*128 + sm)*8] = s1;
    }
    #pragma unroll
    for(int i=0;i<2;i++){
      int kg = bkg + i*2;
      const short* src = Wb + ((size_t)((k0>>3) + kg)*Nn + n0 + bn)*8;
      *(short8*)&Bs[(kg*128 + bn)*8] = *(const short8*)src;
    }
    __syncthreads();
    const int kgl = lane >> 4, ml = lane & 15;
    short8 af[4], bf[4];
    #pragma unroll
    for(int t=0;t<4;t++){
      af[t] = *(const short8*)&As[(kgl*128 + waveM*64 + t*16 + ml)*8];
      bf[t] = *(const short8*)&Bs[(kgl*128 + waveN*64 + t*16 + ml)*8];
    }
    #pragma unroll
    for(int tm=0;tm<4;tm++)
      #pragma unroll
      for(int tn=0;tn<4;tn++)
        acc[tm][tn] = __builtin_amdgcn_mfma_f32_16x16x32_bf16(af[tm], bf[tn], acc[tm][tn], 0, 0, 0);
    __syncthreads();
  }
  // epilogue: D col=lane&15, row=(lane>>4)*4+reg  [m89]
  const int kgl = lane >> 4, ml = lane & 15;
  #pragma unroll
  for(int tn=0;tn<4;tn++){
    int n = n0 + waveN*64 + tn*16 + ml;
    float bv = ldi(bias, n);
    #pragma unroll
    for(int tm=0;tm<4;tm++){
      #pragma unroll
      for(int reg=0;reg<4;reg++){
        int m = m0 + waveM*64 + tm*16 + kgl*4 + reg;
        float v = acc[tm][tn][reg] + bv;
        if(RELU) v = fmaxf(v, 0.f);
        if(OUTBF16) ((short*)g_ws)[(size_t)outOff + (size_t)m*Nn + n] = f2bs(v);
        else        g_ws[(size_t)outOff + (size_t)m*Nn + n] = v;
      }
    }
  }
}

// ---------------------------------------------------------------- final 128->3 (H3 bf16), dtype-matched store
__global__ __launch_bounds__(256) void k_final(const void* __restrict__ FW,
    const void* __restrict__ FB, void* __restrict__ out, int outOff){
  __shared__ float wf[128*3];
  __shared__ float bf3[3];
  const int tid = threadIdx.x;
  for(int t=tid; t<384; t+=256) wf[t] = ldi(FW, t);
  if(tid < 3) bf3[tid] = ldi(FB, tid);
  __syncthreads();
  const int p = blockIdx.x*256 + tid;                // grid=32 -> p < 8192 exactly
  const short* h = (const short*)g_ws + H3C_S + (size_t)p*128;
  float a0 = bf3[0], a1 = bf3[1], a2 = bf3[2];
  #pragma unroll 8
  for(int c=0;c<128;c++){
    float x = bs2f(h[c]);
    a0 = fmaf(x, wf[c*3+0], a0);
    a1 = fmaf(x, wf[c*3+1], a1);
    a2 = fmaf(x, wf[c*3+2], a2);
  }
  size_t o = (size_t)outOff + (size_t)p*3;
  if(g_isbf16){
    bf16* ob = (bf16*)out;
    ob[o+0] = __float2bfloat16(a0); ob[o+1] = __float2bfloat16(a1); ob[o+2] = __float2bfloat16(a2);
  } else {
    float* of = (float*)out;
    of[o+0] = a0; of[o+1] = a1; of[o+2] = a2;
  }
}

extern "C" void kernel_launch(void* const* d_in, const int* in_sizes, int n_in,
                              void* d_out, int out_size, void* d_ws, size_t ws_size,
                              hipStream_t stream){
  (void)d_ws; (void)ws_size;
  static const int EXP[21] = {98304, 384,64, 4096,64, 8192,64, 4096,64, 8192,64, 4096,64,
                              196608,1024, 262144,256, 32768,128, 384,3};
  const void* in[21];
  int posmatch = 0;
  bool run = false;
  if(n_in == 21){
    for(int e=0; e<21; e++) posmatch += (in_sizes[e] == EXP[e]) ? 1 : 0;
    if(posmatch == 21){
      for(int e=0; e<21; e++) in[e] = d_in[e];
      run = true;
    } else {
      bool used[21] = {false}; const void* m[21]; bool ok = true;
      for(int e=0; e<21 && ok; e++){
        int hit = -1;
        for(int i2=0; i2<21; i2++)
          if(!used[i2] && in_sizes[i2] == EXP[e]){ hit = i2; break; }
        if(hit < 0) ok = false;
        else { used[hit] = true; m[e] = d_in[hit]; }
      }
      if(ok){ for(int e=0; e<21; e++) in[e] = m[e]; run = true; }
    }
  }
  if(!run){
    float V = 1000.f*(float)n_in + 10.f*(float)posmatch;
    k_diag<<<(out_size+255)/256, 256, 0, stream>>>((bf16*)d_out, out_size, V);
    return;
  }
  const void* pos  = in[0];
  const void* c1w0 = in[1];  const void* c1b0 = in[2];
  const void* c1w1 = in[3];  const void* c1b1 = in[4];
  const void* c2w0 = in[5];  const void* c2b0 = in[6];
  const void* c2w1 = in[7];  const void* c2b1 = in[8];
  const void* c3w0 = in[9];  const void* c3b0 = in[10];
  const void* c3w1 = in[11]; const void* c3b1 = in[12];
  const void* mw0  = in[13]; const void* mb0  = in[14];
  const void* mw1  = in[15]; const void* mb1  = in[16];
  const void* mw2  = in[17]; const void* mb2  = in[18];
  const void* fw   = in[19]; const void* fb   = in[20];

  dim3 b256(256);
  k_sniff<<<1, b256, 0, stream>>>((const unsigned*)pos);
  k_prep<<<128, b256, 0, stream>>>(pos);

  // stage 1 (C=3)
  k_knn<3><<<8192, b256, 0, stream>>>();
  k_stage_pre<3,true><<<8192, b256, 0, stream>>>(pos, 0, 3, 0, c1w0, c1b0);
  k_edge_agg<true><<<2048, b256, 0, stream>>>(c1w1, c1b1, 0);

  // stage 2 (C=64)
  k_knn<64><<<8192, b256, 0, stream>>>();
  k_stage_pre<64,false><<<8192, b256, 0, stream>>>(nullptr, (int)H_O, 192, 0, c2w0, c2b0);
  k_edge_agg<true><<<2048, b256, 0, stream>>>(c2w1, c2b1, 64);

  // stage 3 (C=64)
  k_knn<64><<<8192, b256, 0, stream>>>();
  k_stage_pre<64,false><<<8192, b256, 0, stream>>>(nullptr, (int)H_O, 192, 64, c3w0, c3b0);
  k_edge_agg<false><<<2048, b256, 0, stream>>>(c3w1, c3b1, 128);

  // weight preconvert AFTER stage 3 (targets alias U-region, dead from here on)
  k_wconv<<<768,  b256, 0, stream>>>(mw0, (int)WB1_S, 196608, 10);
  k_wconv<<<1024, b256, 0, stream>>>(mw1, (int)WB2_S, 262144, 8);
  k_wconv<<<128,  b256, 0, stream>>>(mw2, (int)WB3_S, 32768, 7);

  // final MLP: MFMA bf16, chunked M=8192 (4 chunks; H3 bf16 keeps alias span < H_O)
  for(int ch=0; ch<4; ch++){
    int ainOff = (int)(H_O + (size_t)ch*MC*192);
    k_mgemm<false,true ,true ><<<dim3(64,8), b256, 0, stream>>>(ainOff,     (int)WB1_S, mb0, (int)H1C_S, 192, 1024);
    k_mgemm<true ,true ,true ><<<dim3(64,2), b256, 0, stream>>>((int)H1C_S, (int)WB2_S, mb1, (int)H2C_S, 1024, 256);
    k_mgemm<true ,false,true ><<<dim3(64,1), b256, 0, stream>>>((int)H2C_S, (int)WB3_S, mb2, (int)H3C_S, 256, 128);
    k_final<<<32, b256, 0, stream>>>(fw, fb, d_out, ch*MC*3);
  }
}